// Round 16
// baseline (1336.053 us; speedup 1.0000x reference)
//
#include <hip/hip_runtime.h>
#include <stdint.h>

// VQ codebook quantization, MI355X. Inputs FP32: z_e [B][64], codebook [512][64].
// Output FP32 flat: z_q [B][64] | indices [B] | loss [1].
// Round 16: TLP experiment — __launch_bounds__(512,8) forces VGPR<=64 for
// 8 waves/SIMD (4 blocks/CU). Wave owns 16 rows (A-frags 16 VGPR, TPW=1),
// B streams per-g from the ws table (R13-proven), med3 fold (R14-proven),
// 4-step in-wave butterfly (R15-proven), wave-final results (R13-proven).
// Refine: s2 from np-SSE ws table (bit-identical chain in prep), m-chain via
// float4 chunks (ascending-k single-acc FMA preserved) — no ce[64] regs.
// MARGIN 2e-3, batched np-SSE refine, loss path: R12/R14-verbatim.

#define DIM 64
#define NCODE 512
#define RPB 128
#define MARGIN 2e-3f
#define BIAS 64.0f
#define ZEXB 8
// ws layout: cbhi[512*64]u16 | cblo[512*64]u16 | ce2g[512]f32 | s2np[512]f32
#define WS_NEED (NCODE * DIM * 2 * sizeof(unsigned short) + 2 * NCODE * sizeof(float))

typedef __attribute__((ext_vector_type(8))) short short8;
typedef __attribute__((ext_vector_type(4))) float f32x4;
typedef unsigned long long ull;

__device__ __forceinline__ float bf2f(unsigned short u) {
    union { unsigned u; float f; } c; c.u = ((unsigned)u) << 16; return c.f;
}
__device__ __forceinline__ unsigned short f2bf(float f) {
    union { float f; unsigned u; } c; c.f = f;
    unsigned r = c.u + 0x7fffu + ((c.u >> 16) & 1u);   // RNE (finite inputs)
    return (unsigned short)(r >> 16);
}
__device__ __forceinline__ unsigned fkey(float v) {    // monotonic float->u32
    union { float f; unsigned u; } c; c.f = v;
    return c.u ^ ((unsigned)((int)c.u >> 31) | 0x80000000u);
}

// numpy pairwise_sum of x[i]^2, n=64, baseline-SIMD (SSE, nlanes=4) ordering.
__device__ __forceinline__ float np_sumsq64_sse(const float* x) {
    #pragma clang fp contract(off)
    float T[4];
    #pragma unroll
    for (int l = 0; l < 4; ++l) {
        float A[8];
        #pragma unroll
        for (int j = 0; j < 8; ++j) {
            float u = x[4 * j + l];
            float v = x[32 + 4 * j + l];
            A[j] = u * u + v * v;
        }
        T[l] = ((A[0] + A[1]) + (A[2] + A[3])) + ((A[4] + A[5]) + (A[6] + A[7]));
    }
    return (T[0] + T[1]) + (T[2] + T[3]);
}

__global__ void vq_zero_loss(float* __restrict__ out, long long lidx) {
    if (threadIdx.x == 0) out[lidx] = 0.f;
}

// Precompute cbhi/cblo + ce2+BIAS (main) + np-SSE s2 (refine) into ws.
__global__ __launch_bounds__(NCODE) void vq_prep(
    const float* __restrict__ cb, unsigned short* __restrict__ ws)
{
    const int code = threadIdx.x;
    unsigned short* cbhi = ws;
    unsigned short* cblo = ws + NCODE * DIM;
    float* ce2g = (float*)(ws + 2 * NCODE * DIM);
    float* s2np = ce2g + NCODE;

    float ce[64];
    float sp[4];
    #pragma unroll
    for (int cl = 0; cl < 4; ++cl) {
        float s = 0.f;
        #pragma unroll
        for (int ks = 0; ks < 2; ++ks) {
            #pragma unroll
            for (int t = 0; t < 8; ++t) {
                int k = ks * 32 + cl * 8 + t;
                float v = cb[code * DIM + k];
                ce[k] = v;
                unsigned short hb = f2bf(v);
                cbhi[code * DIM + k] = hb;
                cblo[code * DIM + k] = f2bf(v - bf2f(hb));
                s = fmaf(v, v, s);
            }
        }
        sp[cl] = s;
    }
    ce2g[code] = ((sp[0] + sp[1]) + (sp[2] + sp[3])) + BIAS;
    s2np[code] = np_sumsq64_sse(ce);       // numpy-SSE ordering (refine)
}

template <bool PRE>
__global__ __launch_bounds__(512, 8) void vq_main(
    const float* __restrict__ z, const float* __restrict__ cb,
    float* __restrict__ out, const unsigned short* __restrict__ ws,
    long long batch)
{
    __shared__ __align__(16) unsigned short zhi[RPB * DIM];  // 16KB, swizzled
    __shared__ __align__(16) unsigned short zlo[RPB * DIM];  // 16KB, swizzled
    __shared__ float zsq[RPB];
    __shared__ ull cpack[RPB];                               // (bits<<32)|idx
    __shared__ unsigned ck2[RPB];                            // 2nd-best bits
    __shared__ float wsum[8];
    __shared__ int s_flag[RPB];
    __shared__ int s_nflag;
    __shared__ float s_zex[ZEXB][DIM];
    __shared__ ull s_win[ZEXB];

    const int tid = threadIdx.x, lane = tid & 63, wid = tid >> 6;
    const int cl = lane >> 4, l15 = lane & 15;
    const long long R0 = (long long)blockIdx.x * RPB;
    short8* zhi8 = (short8*)zhi;
    short8* zlo8 = (short8*)zlo;

    if (tid == 0) s_nflag = 0;

    // ---- stage z -> LDS bf16 hi/lo (chunk c at slot c^(row&7)); ||z||^2
    #pragma unroll
    for (int p = 0; p < 2; ++p) {
        int L = p * 512 + tid;
        int row = L >> 3, c = L & 7;
        const float4* g = (const float4*)(z + (R0 + row) * DIM + c * 8);
        float4 f0 = g[0], f1 = g[1];
        float v[8] = {f0.x, f0.y, f0.z, f0.w, f1.x, f1.y, f1.z, f1.w};
        short8 h, l;
        float s = 0.f;
        #pragma unroll
        for (int t = 0; t < 8; ++t) {
            unsigned short hb = f2bf(v[t]);
            h[t] = (short)hb;
            l[t] = (short)f2bf(v[t] - bf2f(hb));   // exact residual, then RNE
            s = fmaf(v[t], v[t], s);
        }
        s += __shfl_xor(s, 1);
        s += __shfl_xor(s, 2);
        s += __shfl_xor(s, 4);
        if ((tid & 7) == 0) zsq[row] = s;
        int slot = row * 8 + (c ^ (row & 7));
        zhi8[slot] = h;
        zlo8[slot] = l;
    }
    __syncthreads();

    // ---- A-fragments: wave owns rows [wid*16, wid*16+16), loaded ONCE
    short8 ah0, ah1, al0, al1;
    {
        int arow = wid * 16 + l15;
        int swz = arow & 7;
        int c0 = cl ^ swz, c1 = (4 + cl) ^ swz;
        ah0 = zhi8[arow * 8 + c0];
        ah1 = zhi8[arow * 8 + c1];
        al0 = zlo8[arow * 8 + c0];
        al1 = zlo8[arow * 8 + c1];
    }

    // ---- stream all 512 codes; lane-local med3 fold (R14-proven)
    float b1[4] = {3.4e38f, 3.4e38f, 3.4e38f, 3.4e38f};
    float b2[4] = {3.4e38f, 3.4e38f, 3.4e38f, 3.4e38f};
    unsigned bi[4] = {0, 0, 0, 0};

    const unsigned short* cbhi = ws;
    const unsigned short* cblo = ws + NCODE * DIM;
    const float* ce2g = (const float*)(ws + 2 * NCODE * DIM);

    for (int g = 0; g < 32; ++g) {
        const int code = g * 16 + l15;
        short8 bh0, bh1, bl0, bl1;
        float ce2;
        if constexpr (PRE) {
            bh0 = *(const short8*)(cbhi + code * DIM + cl * 8);
            bh1 = *(const short8*)(cbhi + code * DIM + 32 + cl * 8);
            bl0 = *(const short8*)(cblo + code * DIM + cl * 8);
            bl1 = *(const short8*)(cblo + code * DIM + 32 + cl * 8);
            ce2 = ce2g[code];
        } else {
            float s = 0.f;
            #pragma unroll
            for (int ks = 0; ks < 2; ++ks) {
                const float4* gp = (const float4*)(cb + code * DIM + ks * 32 + cl * 8);
                float4 f0 = gp[0], f1 = gp[1];
                float v[8] = {f0.x, f0.y, f0.z, f0.w, f1.x, f1.y, f1.z, f1.w};
                short8 h, l;
                #pragma unroll
                for (int t = 0; t < 8; ++t) {
                    unsigned short hb = f2bf(v[t]);
                    h[t] = (short)hb;
                    l[t] = (short)f2bf(v[t] - bf2f(hb));
                    s = fmaf(v[t], v[t], s);
                }
                if (ks == 0) { bh0 = h; bl0 = l; } else { bh1 = h; bl1 = l; }
            }
            s += __shfl_xor(s, 16);
            s += __shfl_xor(s, 32);
            ce2 = s + BIAS;
        }

        f32x4 a = {0.f, 0.f, 0.f, 0.f};
        a = __builtin_amdgcn_mfma_f32_16x16x32_bf16(ah0, bh0, a, 0, 0, 0);
        a = __builtin_amdgcn_mfma_f32_16x16x32_bf16(ah1, bh1, a, 0, 0, 0);
        a = __builtin_amdgcn_mfma_f32_16x16x32_bf16(ah0, bl0, a, 0, 0, 0);
        a = __builtin_amdgcn_mfma_f32_16x16x32_bf16(ah1, bl1, a, 0, 0, 0);
        a = __builtin_amdgcn_mfma_f32_16x16x32_bf16(al0, bh0, a, 0, 0, 0);
        a = __builtin_amdgcn_mfma_f32_16x16x32_bf16(al1, bh1, a, 0, 0, 0);

        #pragma unroll
        for (int r = 0; r < 4; ++r) {
            float v = fmaf(-2.f, a[r], ce2);               // positive (bias)
            float nb2 = __builtin_amdgcn_fmed3f(v, b1[r], b2[r]);
            bi[r] = (v < b1[r]) ? (unsigned)code : bi[r];  // g asc: first-idx
            b1[r] = fminf(v, b1[r]);
            b2[r] = nb2;
        }
    }

    // ---- 4-step 16-lane butterfly per r (R15-proven ops); wave-final
    #pragma unroll
    for (int r = 0; r < 4; ++r) {
        float x1 = b1[r], x2 = b2[r];
        unsigned xi = bi[r];
        #pragma unroll
        for (int m = 1; m <= 8; m <<= 1) {
            float ob  = __shfl_xor(x1, m);
            float ob2 = __shfl_xor(x2, m);
            unsigned oi = __shfl_xor(xi, m);
            float mx = fmaxf(x1, ob);
            x2 = fminf(fminf(x2, ob2), mx);
            xi = (ob < x1) ? oi : xi;
            x1 = fminf(x1, ob);
        }
        if (l15 == 0) {
            int row = wid * 16 + cl * 4 + r;               // C/D layout (m89)
            cpack[row] = ((ull)__float_as_uint(x1) << 32) | xi;
            ck2[row] = __float_as_uint(x2);
        }
    }
    __syncthreads();

    // ---- phase 2: z_q, idx, flag, loss (R14-verbatim)
    {
        int row = tid >> 2, j = tid & 3;
        ull best = cpack[row];
        unsigned bk2 = ck2[row];
        unsigned code = (unsigned)best;
        long long grow = R0 + row;

        float4* out4 = (float4*)out;
        const float4* cb4 = (const float4*)cb;
        #pragma unroll
        for (int t = 0; t < 4; ++t)
            out4[grow * 16 + j * 4 + t] = cb4[(long long)code * 16 + j * 4 + t];

        float d = 0.f;
        if (j == 0) {
            out[batch * DIM + grow] = (float)code;       // index as exact float
            float v1b = __uint_as_float((unsigned)(best >> 32));
            float v2b = __uint_as_float(bk2);
            d = zsq[row] + (v1b - BIAS);                 // ~min distance (loss)
            if (v2b - v1b < MARGIN) {                    // ambiguous -> np-emulate
                int p = atomicAdd(&s_nflag, 1);
                s_flag[p] = row;
            }
        }
        #pragma unroll
        for (int m = 1; m < 64; m <<= 1) d += __shfl_xor(d, m);
        if (lane == 0) wsum[wid] = d;
    }
    __syncthreads();
    if (tid == 0) {
        float s = 0.f;
        #pragma unroll
        for (int w = 0; w < 8; ++w) s += wsum[w];
        atomicAdd(&out[batch * DIM + batch], s * (1.0f / 67108864.0f)); // B*DIM=2^26
    }

    // ---- in-block np-fp32-emulated re-rank of flagged rows.
    // Same math/order as R12-R15; m-chain reads cb in float4 chunks
    // (ascending-k, single accumulator); s2 from prep table (bit-identical).
    int nf = s_nflag;
    if (nf > 0) {
        const float4* cb4 = (const float4*)cb;
        float s2;
        if constexpr (PRE) {
            s2 = ((const float*)(ws + 2 * NCODE * DIM))[NCODE + tid];
        } else {
            // chunked np-SSE sumsq (identical op chains, vectorized over l)
            #pragma clang fp contract(off)
            float4 A[8];
            #pragma unroll
            for (int j = 0; j < 8; ++j) {
                float4 u = cb4[tid * 16 + j];
                float4 v = cb4[tid * 16 + 8 + j];
                A[j].x = u.x * u.x + v.x * v.x;
                A[j].y = u.y * u.y + v.y * v.y;
                A[j].z = u.z * u.z + v.z * v.z;
                A[j].w = u.w * u.w + v.w * v.w;
            }
            float4 T;
            T.x = ((A[0].x + A[1].x) + (A[2].x + A[3].x)) + ((A[4].x + A[5].x) + (A[6].x + A[7].x));
            T.y = ((A[0].y + A[1].y) + (A[2].y + A[3].y)) + ((A[4].y + A[5].y) + (A[6].y + A[7].y));
            T.z = ((A[0].z + A[1].z) + (A[2].z + A[3].z)) + ((A[4].z + A[5].z) + (A[6].z + A[7].z));
            T.w = ((A[0].w + A[1].w) + (A[2].w + A[3].w)) + ((A[4].w + A[5].w) + (A[6].w + A[7].w));
            s2 = (T.x + T.y) + (T.z + T.w);
        }

        for (int b0 = 0; b0 < nf; b0 += ZEXB) {
            int nb = min(ZEXB, nf - b0);
            if (tid < nb * 64) {
                int i = tid >> 6, l2 = tid & 63;
                s_zex[i][l2] = z[(R0 + s_flag[b0 + i]) * DIM + l2];  // exact fp32
            }
            if (tid < ZEXB) s_win[tid] = ~0ull;
            __syncthreads();

            for (int i = 0; i < nb; ++i) {
                float s1 = np_sumsq64_sse(&s_zex[i][0]); // np sum(z^2), SSE order
                float m = 0.f;                           // sgemm: ascending-k FMA
                #pragma unroll
                for (int q = 0; q < 16; ++q) {
                    float4 e = cb4[tid * 16 + q];
                    m = __builtin_fmaf(s_zex[i][q * 4 + 0], e.x, m);
                    m = __builtin_fmaf(s_zex[i][q * 4 + 1], e.y, m);
                    m = __builtin_fmaf(s_zex[i][q * 4 + 2], e.z, m);
                    m = __builtin_fmaf(s_zex[i][q * 4 + 3], e.w, m);
                }
                float dnp;
                {
                    #pragma clang fp contract(off)
                    float tt = s1 - 2.0f * m;            // keep as mul+sub (no fma)
                    dnp = tt + s2;
                }
                ull key = ((ull)fkey(dnp) << 10) | (unsigned)tid;
                #pragma unroll
                for (int mm = 1; mm < 64; mm <<= 1) {
                    ull o = __shfl_xor(key, mm);
                    if (o < key) key = o;
                }
                if (lane == 0) atomicMin(&s_win[i], key);
            }
            __syncthreads();

            for (int i = wid; i < nb; i += 8) {          // apply winners
                unsigned code = (unsigned)(s_win[i] & 0x3FFull);
                int rowb = s_flag[b0 + i];
                long long grow = R0 + rowb;
                out[grow * DIM + lane] = cb[(long long)code * DIM + lane];
                if (lane == 0) out[batch * DIM + grow] = (float)code;
            }
            __syncthreads();
        }
    }
}

extern "C" void kernel_launch(void* const* d_in, const int* in_sizes, int n_in,
                              void* d_out, int out_size, void* d_ws, size_t ws_size,
                              hipStream_t stream)
{
    const float* z  = (const float*)d_in[0];
    const float* cb = (const float*)d_in[1];
    float* out = (float*)d_out;
    unsigned short* ws = (unsigned short*)d_ws;

    long long batch = (long long)in_sizes[0] / DIM;
    int nblocks = (int)(batch / RPB);
    long long lidx = batch * DIM + batch;

    vq_zero_loss<<<1, 64, 0, stream>>>(out, lidx);
    if (d_ws != nullptr && ws_size >= WS_NEED) {
        vq_prep<<<1, NCODE, 0, stream>>>(cb, ws);
        vq_main<true><<<nblocks, 512, 0, stream>>>(z, cb, out, ws, batch);
    } else {
        vq_main<false><<<nblocks, 512, 0, stream>>>(z, cb, out, ws, batch);
    }
}

// Round 17
// 703.953 us; speedup vs baseline: 1.8979x; 1.8979x over previous
//
#include <hip/hip_runtime.h>
#include <stdint.h>

// VQ codebook quantization, MI355X. Inputs FP32: z_e [B][64], codebook [512][64].
// Output FP32 flat: z_q [B][64] | indices [B] | loss [1].
// Round 17 = R15 + occupancy fix: (1) __launch_bounds__(512,4) caps unified
// VGPR at 128 (R16 proved residency tracks unified VGPR: 32->81% occ but
// spilled; 80+~64 AGPR -> 22%); (2) per-ct immediate fold keeps ONE acc tile
// live (4 AGPR instead of ~64) -> fits the <=128 bucket = 4 waves/SIMD =
// 2 blocks/CU. Fold order unchanged (ct ascending) -> bit-identical results.
// Staging, prep table, butterfly, phase 2, batched np-SSE refine, loss:
// R15-verbatim.

#define DIM 64
#define NCODE 512
#define RPB 128
#define MARGIN 2e-3f
#define BIAS 64.0f
#define ZEXB 8
#define WS_NEED (NCODE * DIM * 2 * sizeof(unsigned short) + NCODE * sizeof(float))

typedef __attribute__((ext_vector_type(8))) short short8;
typedef __attribute__((ext_vector_type(4))) float f32x4;
typedef unsigned long long ull;

__device__ __forceinline__ float bf2f(unsigned short u) {
    union { unsigned u; float f; } c; c.u = ((unsigned)u) << 16; return c.f;
}
__device__ __forceinline__ unsigned short f2bf(float f) {
    union { float f; unsigned u; } c; c.f = f;
    unsigned r = c.u + 0x7fffu + ((c.u >> 16) & 1u);   // RNE (finite inputs)
    return (unsigned short)(r >> 16);
}
__device__ __forceinline__ unsigned fkey(float v) {    // monotonic float->u32
    union { float f; unsigned u; } c; c.f = v;
    return c.u ^ ((unsigned)((int)c.u >> 31) | 0x80000000u);
}

// numpy pairwise_sum of x[i]^2, n=64, baseline-SIMD (SSE, nlanes=4) ordering.
__device__ __forceinline__ float np_sumsq64_sse(const float* x) {
    #pragma clang fp contract(off)
    float T[4];
    #pragma unroll
    for (int l = 0; l < 4; ++l) {
        float A[8];
        #pragma unroll
        for (int j = 0; j < 8; ++j) {
            float u = x[4 * j + l];
            float v = x[32 + 4 * j + l];
            A[j] = u * u + v * v;
        }
        T[l] = ((A[0] + A[1]) + (A[2] + A[3])) + ((A[4] + A[5]) + (A[6] + A[7]));
    }
    return (T[0] + T[1]) + (T[2] + T[3]);
}

__global__ void vq_zero_loss(float* __restrict__ out, long long lidx) {
    if (threadIdx.x == 0) out[lidx] = 0.f;
}

// Precompute cbhi/cblo (bf16 bits) + ce2+BIAS (f32) into ws — R12/R14-proven.
__global__ __launch_bounds__(NCODE) void vq_prep(
    const float* __restrict__ cb, unsigned short* __restrict__ ws)
{
    const int code = threadIdx.x;
    unsigned short* cbhi = ws;
    unsigned short* cblo = ws + NCODE * DIM;
    float* ce2g = (float*)(ws + 2 * NCODE * DIM);

    float sp[4];
    #pragma unroll
    for (int cl = 0; cl < 4; ++cl) {
        float s = 0.f;
        #pragma unroll
        for (int ks = 0; ks < 2; ++ks) {
            #pragma unroll
            for (int t = 0; t < 8; ++t) {
                int k = ks * 32 + cl * 8 + t;
                float v = cb[code * DIM + k];
                unsigned short hb = f2bf(v);
                cbhi[code * DIM + k] = hb;
                cblo[code * DIM + k] = f2bf(v - bf2f(hb));
                s = fmaf(v, v, s);
            }
        }
        sp[cl] = s;
    }
    ce2g[code] = ((sp[0] + sp[1]) + (sp[2] + sp[3])) + BIAS;
}

template <bool PRE>
__global__ __launch_bounds__(512, 4) void vq_main(
    const float* __restrict__ z, const float* __restrict__ cb,
    float* __restrict__ out, const unsigned short* __restrict__ ws,
    long long batch)
{
    __shared__ __align__(16) unsigned short zhi[RPB * DIM];  // 16KB, swizzled
    __shared__ __align__(16) unsigned short zlo[RPB * DIM];  // 16KB, swizzled
    __shared__ float zsq[RPB];
    __shared__ float arrB[RPB][9];                           // per-(row,wave) best
    __shared__ float arrB2[RPB][9];                          // per-(row,wave) 2nd
    __shared__ unsigned arrI[RPB][9];                        // per-(row,wave) idx
    __shared__ ull cpack[RPB];                               // (bits<<32)|idx
    __shared__ unsigned ck2[RPB];                            // 2nd-best bits
    __shared__ float wsum[8];
    __shared__ int s_flag[RPB];
    __shared__ int s_nflag;
    __shared__ float s_zex[ZEXB][DIM];
    __shared__ ull s_win[ZEXB];

    const int tid = threadIdx.x, lane = tid & 63, wid = tid >> 6;
    const long long R0 = (long long)blockIdx.x * RPB;
    short8* zhi8 = (short8*)zhi;
    short8* zlo8 = (short8*)zlo;

    if (tid == 0) s_nflag = 0;

    // ---- stage z -> LDS bf16 hi/lo (chunk c at slot c^(row&7)); ||z||^2
    #pragma unroll
    for (int p = 0; p < 2; ++p) {
        int L = p * 512 + tid;
        int row = L >> 3, c = L & 7;
        const float4* g = (const float4*)(z + (R0 + row) * DIM + c * 8);
        float4 f0 = g[0], f1 = g[1];
        float v[8] = {f0.x, f0.y, f0.z, f0.w, f1.x, f1.y, f1.z, f1.w};
        short8 h, l;
        float s = 0.f;
        #pragma unroll
        for (int t = 0; t < 8; ++t) {
            unsigned short hb = f2bf(v[t]);
            h[t] = (short)hb;
            l[t] = (short)f2bf(v[t] - bf2f(hb));   // exact residual, then RNE
            s = fmaf(v[t], v[t], s);
        }
        s += __shfl_xor(s, 1);
        s += __shfl_xor(s, 2);
        s += __shfl_xor(s, 4);
        if ((tid & 7) == 0) zsq[row] = s;
        int slot = row * 8 + (c ^ (row & 7));
        zhi8[slot] = h;
        zlo8[slot] = l;
    }

    // ---- B fragments: wave owns codes [wid*64, wid*64+64), hi/lo + ||e||^2+64
    short8 bhi[4][2], blo[4][2];
    float ce2[4];
    if constexpr (PRE) {
        const unsigned short* cbhi = ws;
        const unsigned short* cblo = ws + NCODE * DIM;
        const float* ce2g = (const float*)(ws + 2 * NCODE * DIM);
        #pragma unroll
        for (int ct = 0; ct < 4; ++ct) {
            int code = wid * 64 + ct * 16 + (lane & 15);
            #pragma unroll
            for (int ks = 0; ks < 2; ++ks) {
                int k = ks * 32 + (lane >> 4) * 8;
                bhi[ct][ks] = *(const short8*)(cbhi + code * DIM + k);
                blo[ct][ks] = *(const short8*)(cblo + code * DIM + k);
            }
            ce2[ct] = ce2g[code];
        }
    } else {
        #pragma unroll
        for (int ct = 0; ct < 4; ++ct) {
            int code = wid * 64 + ct * 16 + (lane & 15);
            float s = 0.f;
            #pragma unroll
            for (int ks = 0; ks < 2; ++ks) {
                int k = ks * 32 + (lane >> 4) * 8;
                const float4* g = (const float4*)(cb + code * DIM + k);
                float4 f0 = g[0], f1 = g[1];
                float v[8] = {f0.x, f0.y, f0.z, f0.w, f1.x, f1.y, f1.z, f1.w};
                short8 h, l;
                #pragma unroll
                for (int t = 0; t < 8; ++t) {
                    unsigned short hb = f2bf(v[t]);
                    h[t] = (short)hb;
                    l[t] = (short)f2bf(v[t] - bf2f(hb));
                    s = fmaf(v[t], v[t], s);
                }
                bhi[ct][ks] = h;
                blo[ct][ks] = l;
            }
            s += __shfl_xor(s, 16);
            s += __shfl_xor(s, 32);
            ce2[ct] = s + BIAS;
        }
    }

    __syncthreads();

    // ---- phase 1: 8 row-tiles, NO barriers. Per ct: 6 MFMA -> immediate
    // fold (ONE acc tile live -> minimal AGPR). Then 16-lane butterfly.
    for (int rt = 0; rt < 8; ++rt) {
        int arow = rt * 16 + (lane & 15);
        int swz = arow & 7;
        int c0 = (lane >> 4) ^ swz, c1 = (4 + (lane >> 4)) ^ swz;
        short8 ah0 = zhi8[arow * 8 + c0], ah1 = zhi8[arow * 8 + c1];
        short8 al0 = zlo8[arow * 8 + c0], al1 = zlo8[arow * 8 + c1];

        float b1[4] = {3.4e38f, 3.4e38f, 3.4e38f, 3.4e38f};
        float b2[4] = {3.4e38f, 3.4e38f, 3.4e38f, 3.4e38f};
        unsigned bi[4] = {0, 0, 0, 0};

        #pragma unroll
        for (int ct = 0; ct < 4; ++ct) {
            f32x4 a = {0.f, 0.f, 0.f, 0.f};
            a = __builtin_amdgcn_mfma_f32_16x16x32_bf16(ah0, bhi[ct][0], a, 0, 0, 0);
            a = __builtin_amdgcn_mfma_f32_16x16x32_bf16(ah1, bhi[ct][1], a, 0, 0, 0);
            a = __builtin_amdgcn_mfma_f32_16x16x32_bf16(ah0, blo[ct][0], a, 0, 0, 0);
            a = __builtin_amdgcn_mfma_f32_16x16x32_bf16(ah1, blo[ct][1], a, 0, 0, 0);
            a = __builtin_amdgcn_mfma_f32_16x16x32_bf16(al0, bhi[ct][0], a, 0, 0, 0);
            a = __builtin_amdgcn_mfma_f32_16x16x32_bf16(al1, bhi[ct][1], a, 0, 0, 0);
            #pragma unroll
            for (int r = 0; r < 4; ++r) {
                float v = fmaf(-2.f, a[r], ce2[ct]);           // positive (bias)
                unsigned idx = (unsigned)(wid * 64 + ct * 16 + (lane & 15));
                float nb2 = __builtin_amdgcn_fmed3f(v, b1[r], b2[r]);
                bi[r] = (v < b1[r]) ? idx : bi[r];             // ct asc: first-idx
                b1[r] = fminf(v, b1[r]);
                b2[r] = nb2;
            }
        }

        // full 16-lane butterfly (m = 1,2,4,8), exact (min,2nd-min)
        #pragma unroll
        for (int r = 0; r < 4; ++r) {
            float x1 = b1[r], x2 = b2[r];
            unsigned xi = bi[r];
            #pragma unroll
            for (int m = 1; m <= 8; m <<= 1) {
                float ob  = __shfl_xor(x1, m);
                float ob2 = __shfl_xor(x2, m);
                unsigned oi = __shfl_xor(xi, m);
                float mx = fmaxf(x1, ob);
                x2 = fminf(fminf(x2, ob2), mx);
                xi = (ob < x1) ? oi : xi;
                x1 = fminf(x1, ob);
            }
            if ((lane & 15) == 0) {
                int row = rt * 16 + (lane >> 4) * 4 + r;   // C/D layout (m89)
                arrB[row][wid]  = x1;
                arrB2[row][wid] = x2;
                arrI[row][wid]  = xi;
            }
        }
    }
    __syncthreads();

    // ---- final merge: 128 threads, one row each, scan 8 wave-entries
    if (tid < 128) {
        int row = tid;
        float b1 = arrB[row][0], b2 = arrB2[row][0];
        unsigned bi = arrI[row][0];
        #pragma unroll
        for (int w = 1; w < 8; ++w) {
            float ob = arrB[row][w];
            float ob2 = arrB2[row][w];
            unsigned oi = arrI[row][w];
            float mx = fmaxf(b1, ob);
            b2 = fminf(fminf(b2, ob2), mx);
            bi = (ob < b1) ? oi : bi;
            b1 = fminf(b1, ob);
        }
        cpack[row] = ((ull)__float_as_uint(b1) << 32) | bi;
        ck2[row] = __float_as_uint(b2);
    }
    __syncthreads();

    // ---- phase 2: z_q, idx, flag, loss (R14-verbatim)
    {
        int row = tid >> 2, j = tid & 3;
        ull best = cpack[row];
        unsigned bk2 = ck2[row];
        unsigned code = (unsigned)best;
        long long grow = R0 + row;

        float4* out4 = (float4*)out;
        const float4* cb4 = (const float4*)cb;
        #pragma unroll
        for (int t = 0; t < 4; ++t)
            out4[grow * 16 + j * 4 + t] = cb4[(long long)code * 16 + j * 4 + t];

        float d = 0.f;
        if (j == 0) {
            out[batch * DIM + grow] = (float)code;       // index as exact float
            float v1b = __uint_as_float((unsigned)(best >> 32));
            float v2b = __uint_as_float(bk2);
            d = zsq[row] + (v1b - BIAS);                 // ~min distance (loss)
            if (v2b - v1b < MARGIN) {                    // ambiguous -> np-emulate
                int p = atomicAdd(&s_nflag, 1);
                s_flag[p] = row;
            }
        }
        #pragma unroll
        for (int m = 1; m < 64; m <<= 1) d += __shfl_xor(d, m);
        if (lane == 0) wsum[wid] = d;
    }
    __syncthreads();
    if (tid == 0) {
        float s = 0.f;
        #pragma unroll
        for (int w = 0; w < 8; ++w) s += wsum[w];
        atomicAdd(&out[batch * DIM + batch], s * (1.0f / 67108864.0f)); // B*DIM=2^26
    }

    // ---- in-block np-fp32-emulated re-rank of flagged rows (R14-verbatim)
    int nf = s_nflag;
    if (nf > 0) {
        float ce[64];                                    // thread's code row (tid==code)
        const float4* cb4 = (const float4*)cb;
        #pragma unroll
        for (int q = 0; q < 16; ++q) {
            float4 v = cb4[tid * 16 + q];
            ce[q * 4 + 0] = v.x; ce[q * 4 + 1] = v.y;
            ce[q * 4 + 2] = v.z; ce[q * 4 + 3] = v.w;
        }
        float s2 = np_sumsq64_sse(ce);                   // np sum(cb^2), SSE order

        for (int b0 = 0; b0 < nf; b0 += ZEXB) {
            int nb = min(ZEXB, nf - b0);
            if (tid < nb * 64) {
                int i = tid >> 6, l2 = tid & 63;
                s_zex[i][l2] = z[(R0 + s_flag[b0 + i]) * DIM + l2];  // exact fp32
            }
            if (tid < ZEXB) s_win[tid] = ~0ull;
            __syncthreads();

            for (int i = 0; i < nb; ++i) {
                float s1 = np_sumsq64_sse(&s_zex[i][0]); // np sum(z^2), SSE order
                float m = 0.f;                           // sgemm: ascending-k FMA
                #pragma unroll
                for (int k = 0; k < 64; ++k)
                    m = __builtin_fmaf(s_zex[i][k], ce[k], m);
                float dnp;
                {
                    #pragma clang fp contract(off)
                    float tt = s1 - 2.0f * m;            // keep as mul+sub (no fma)
                    dnp = tt + s2;
                }
                ull key = ((ull)fkey(dnp) << 10) | (unsigned)tid;
                #pragma unroll
                for (int mm = 1; mm < 64; mm <<= 1) {
                    ull o = __shfl_xor(key, mm);
                    if (o < key) key = o;
                }
                if (lane == 0) atomicMin(&s_win[i], key);
            }
            __syncthreads();

            for (int i = wid; i < nb; i += 8) {          // apply winners
                unsigned code = (unsigned)(s_win[i] & 0x3FFull);
                int rowb = s_flag[b0 + i];
                long long grow = R0 + rowb;
                out[grow * DIM + lane] = cb[(long long)code * DIM + lane];
                if (lane == 0) out[batch * DIM + grow] = (float)code;
            }
            __syncthreads();
        }
    }
}

extern "C" void kernel_launch(void* const* d_in, const int* in_sizes, int n_in,
                              void* d_out, int out_size, void* d_ws, size_t ws_size,
                              hipStream_t stream)
{
    const float* z  = (const float*)d_in[0];
    const float* cb = (const float*)d_in[1];
    float* out = (float*)d_out;
    unsigned short* ws = (unsigned short*)d_ws;

    long long batch = (long long)in_sizes[0] / DIM;
    int nblocks = (int)(batch / RPB);
    long long lidx = batch * DIM + batch;

    vq_zero_loss<<<1, 64, 0, stream>>>(out, lidx);
    if (d_ws != nullptr && ws_size >= WS_NEED) {
        vq_prep<<<1, NCODE, 0, stream>>>(cb, ws);
        vq_main<true><<<nblocks, 512, 0, stream>>>(z, cb, out, ws, batch);
    } else {
        vq_main<false><<<nblocks, 512, 0, stream>>>(z, cb, out, ws, batch);
    }
}

// Round 19
// 602.166 us; speedup vs baseline: 2.2187x; 1.1690x over previous
//
#include <hip/hip_runtime.h>
#include <stdint.h>

// VQ codebook quantization, MI355X. Inputs FP32: z_e [B][64], codebook [512][64].
// Output FP32 flat: z_q [B][64] | indices [B] | loss [1].
// Round 19 = R18 with the vq_part inter-wave merge BUG FIXED: per-(row,wave)
// results now go to LDS slices (single-writer), one barrier, then threads
// 0..63 merge the 4 wave entries (w asc = code asc, strict < = first-index)
// and write the per-(row,half) record to wsP. vq_merge unchanged (2-half
// merge + R12-verbatim phase 2 + np-SSE refine + loss). Fallback: R17-proven
// mono kernel when ws too small.

#define DIM 64
#define NCODE 512
#define RPB 128
#define PRPB 64                       // rows per vq_part block
#define MARGIN 2e-3f
#define BIAS 64.0f
#define ZEXB 8
#define WS_TAB (NCODE * DIM * 2 * sizeof(unsigned short) + NCODE * sizeof(float))

typedef __attribute__((ext_vector_type(8))) short short8;
typedef __attribute__((ext_vector_type(4))) float f32x4;
typedef unsigned long long ull;

__device__ __forceinline__ float bf2f(unsigned short u) {
    union { unsigned u; float f; } c; c.u = ((unsigned)u) << 16; return c.f;
}
__device__ __forceinline__ unsigned short f2bf(float f) {
    union { float f; unsigned u; } c; c.f = f;
    unsigned r = c.u + 0x7fffu + ((c.u >> 16) & 1u);   // RNE (finite inputs)
    return (unsigned short)(r >> 16);
}
__device__ __forceinline__ unsigned fkey(float v) {    // monotonic float->u32
    union { float f; unsigned u; } c; c.f = v;
    return c.u ^ ((unsigned)((int)c.u >> 31) | 0x80000000u);
}

// numpy pairwise_sum of x[i]^2, n=64, baseline-SIMD (SSE, nlanes=4) ordering.
__device__ __forceinline__ float np_sumsq64_sse(const float* x) {
    #pragma clang fp contract(off)
    float T[4];
    #pragma unroll
    for (int l = 0; l < 4; ++l) {
        float A[8];
        #pragma unroll
        for (int j = 0; j < 8; ++j) {
            float u = x[4 * j + l];
            float v = x[32 + 4 * j + l];
            A[j] = u * u + v * v;
        }
        T[l] = ((A[0] + A[1]) + (A[2] + A[3])) + ((A[4] + A[5]) + (A[6] + A[7]));
    }
    return (T[0] + T[1]) + (T[2] + T[3]);
}

__global__ void vq_zero_loss(float* __restrict__ out, long long lidx) {
    if (threadIdx.x == 0) out[lidx] = 0.f;
}

// Precompute cbhi/cblo (bf16 bits) + ce2+BIAS (f32) into ws — proven R14-R17.
__global__ __launch_bounds__(NCODE) void vq_prep(
    const float* __restrict__ cb, unsigned short* __restrict__ ws)
{
    const int code = threadIdx.x;
    unsigned short* cbhi = ws;
    unsigned short* cblo = ws + NCODE * DIM;
    float* ce2g = (float*)(ws + 2 * NCODE * DIM);

    float sp[4];
    #pragma unroll
    for (int cl = 0; cl < 4; ++cl) {
        float s = 0.f;
        #pragma unroll
        for (int ks = 0; ks < 2; ++ks) {
            #pragma unroll
            for (int t = 0; t < 8; ++t) {
                int k = ks * 32 + cl * 8 + t;
                float v = cb[code * DIM + k];
                unsigned short hb = f2bf(v);
                cbhi[code * DIM + k] = hb;
                cblo[code * DIM + k] = f2bf(v - bf2f(hb));
                s = fmaf(v, v, s);
            }
        }
        sp[cl] = s;
    }
    ce2g[code] = ((sp[0] + sp[1]) + (sp[2] + sp[3])) + BIAS;
}

// ---- phase A: 256-thr blocks, 64 rows x 256 codes (bid&1 = code half).
__global__ __launch_bounds__(256) void vq_part(
    const float* __restrict__ z, const unsigned short* __restrict__ ws,
    unsigned* __restrict__ wsP, float* __restrict__ out,
    long long batch, long long lidx)
{
    __shared__ __align__(16) unsigned short zhi[PRPB * DIM];  // 8KB, swizzled
    __shared__ __align__(16) unsigned short zlo[PRPB * DIM];  // 8KB, swizzled
    __shared__ float zsq[PRPB];
    __shared__ float arrB[PRPB][5];                           // [row][wave], padded
    __shared__ float arrB2[PRPB][5];
    __shared__ unsigned arrI[PRPB][5];

    const int tid = threadIdx.x, lane = tid & 63, wid = tid >> 6;
    const int cl = lane >> 4, l15 = lane & 15;
    const int bid = blockIdx.x;
    const int half = bid & 1;
    const long long R0 = (long long)(bid >> 1) * PRPB;
    short8* zhi8 = (short8*)zhi;
    short8* zlo8 = (short8*)zlo;

    // ---- stage z -> LDS bf16 hi/lo (chunk c at slot c^(row&7)); ||z||^2
    #pragma unroll
    for (int p = 0; p < 2; ++p) {
        int L = p * 256 + tid;
        int row = L >> 3, c = L & 7;
        const float4* g = (const float4*)(z + (R0 + row) * DIM + c * 8);
        float4 f0 = g[0], f1 = g[1];
        float v[8] = {f0.x, f0.y, f0.z, f0.w, f1.x, f1.y, f1.z, f1.w};
        short8 h, l;
        float s = 0.f;
        #pragma unroll
        for (int t = 0; t < 8; ++t) {
            unsigned short hb = f2bf(v[t]);
            h[t] = (short)hb;
            l[t] = (short)f2bf(v[t] - bf2f(hb));   // exact residual, then RNE
            s = fmaf(v[t], v[t], s);
        }
        s += __shfl_xor(s, 1);
        s += __shfl_xor(s, 2);
        s += __shfl_xor(s, 4);
        if ((tid & 7) == 0) zsq[row] = s;
        int slot = row * 8 + (c ^ (row & 7));
        zhi8[slot] = h;
        zlo8[slot] = l;
    }

    // ---- B fragments: wave owns codes half*256 + [wid*64, wid*64+64)
    short8 bhi[4][2], blo[4][2];
    float ce2[4];
    {
        const unsigned short* cbhi = ws;
        const unsigned short* cblo = ws + NCODE * DIM;
        const float* ce2g = (const float*)(ws + 2 * NCODE * DIM);
        #pragma unroll
        for (int ct = 0; ct < 4; ++ct) {
            int code = half * 256 + wid * 64 + ct * 16 + l15;
            #pragma unroll
            for (int ks = 0; ks < 2; ++ks) {
                int k = ks * 32 + cl * 8;
                bhi[ct][ks] = *(const short8*)(cbhi + code * DIM + k);
                blo[ct][ks] = *(const short8*)(cblo + code * DIM + k);
            }
            ce2[ct] = ce2g[code];
        }
    }
    __syncthreads();

    // ---- block loss partial (half 0 only): sum zsq, one atomic
    if (half == 0 && tid < PRPB) {
        float v = zsq[tid];
        #pragma unroll
        for (int m = 1; m < 64; m <<= 1) v += __shfl_xor(v, m);
        if (lane == 0) atomicAdd(&out[lidx], v * (1.0f / 67108864.0f));
    }

    // ---- 4 row-tiles: per-ct immediate fold (R17-proven) + butterfly;
    // per-(row,wave) result into LDS slice (single-writer slot)
    for (int rt = 0; rt < 4; ++rt) {
        int arow = rt * 16 + l15;
        int swz = arow & 7;
        int c0 = cl ^ swz, c1 = (4 + cl) ^ swz;
        short8 ah0 = zhi8[arow * 8 + c0], ah1 = zhi8[arow * 8 + c1];
        short8 al0 = zlo8[arow * 8 + c0], al1 = zlo8[arow * 8 + c1];

        float b1[4] = {3.4e38f, 3.4e38f, 3.4e38f, 3.4e38f};
        float b2[4] = {3.4e38f, 3.4e38f, 3.4e38f, 3.4e38f};
        unsigned bi[4] = {0, 0, 0, 0};

        #pragma unroll
        for (int ct = 0; ct < 4; ++ct) {
            f32x4 a = {0.f, 0.f, 0.f, 0.f};
            a = __builtin_amdgcn_mfma_f32_16x16x32_bf16(ah0, bhi[ct][0], a, 0, 0, 0);
            a = __builtin_amdgcn_mfma_f32_16x16x32_bf16(ah1, bhi[ct][1], a, 0, 0, 0);
            a = __builtin_amdgcn_mfma_f32_16x16x32_bf16(ah0, blo[ct][0], a, 0, 0, 0);
            a = __builtin_amdgcn_mfma_f32_16x16x32_bf16(ah1, blo[ct][1], a, 0, 0, 0);
            a = __builtin_amdgcn_mfma_f32_16x16x32_bf16(al0, bhi[ct][0], a, 0, 0, 0);
            a = __builtin_amdgcn_mfma_f32_16x16x32_bf16(al1, bhi[ct][1], a, 0, 0, 0);
            #pragma unroll
            for (int r = 0; r < 4; ++r) {
                float v = fmaf(-2.f, a[r], ce2[ct]);           // positive (bias)
                unsigned idx = (unsigned)(half * 256 + wid * 64 + ct * 16 + l15);
                float nb2 = __builtin_amdgcn_fmed3f(v, b1[r], b2[r]);
                bi[r] = (v < b1[r]) ? idx : bi[r];             // ct asc
                b1[r] = fminf(v, b1[r]);
                b2[r] = nb2;
            }
        }

        #pragma unroll
        for (int r = 0; r < 4; ++r) {
            float x1 = b1[r], x2 = b2[r];
            unsigned xi = bi[r];
            #pragma unroll
            for (int m = 1; m <= 8; m <<= 1) {
                float ob  = __shfl_xor(x1, m);
                float ob2 = __shfl_xor(x2, m);
                unsigned oi = __shfl_xor(xi, m);
                float mx = fmaxf(x1, ob);
                x2 = fminf(fminf(x2, ob2), mx);
                xi = (ob < x1) ? oi : xi;
                x1 = fminf(x1, ob);
            }
            if (l15 == 0) {
                int row = rt * 16 + cl * 4 + r;                // C/D layout (m89)
                arrB[row][wid]  = x1;
                arrB2[row][wid] = x2;
                arrI[row][wid]  = xi;
            }
        }
    }
    __syncthreads();

    // ---- inter-wave merge (THE R18 FIX): threads 0..63, one row each;
    // scan w ascending (= code ascending), strict < keeps first index.
    if (tid < PRPB) {
        int row = tid;
        float b1 = arrB[row][0], b2 = arrB2[row][0];
        unsigned bi = arrI[row][0];
        #pragma unroll
        for (int w = 1; w < 4; ++w) {
            float ob = arrB[row][w];
            float ob2 = arrB2[row][w];
            unsigned oi = arrI[row][w];
            float mx = fmaxf(b1, ob);
            b2 = fminf(fminf(b2, ob2), mx);
            bi = (ob < b1) ? oi : bi;
            b1 = fminf(b1, ob);
        }
        unsigned* p = wsP + ((R0 + row) * 2 + half) * 3;
        p[0] = __float_as_uint(b1);
        p[1] = __float_as_uint(b2);
        p[2] = bi;
    }
}

// ---- phase B: merge halves, phase-2 outputs, in-block refine (R12-verbatim)
__global__ __launch_bounds__(512) void vq_merge(
    const float* __restrict__ z, const float* __restrict__ cb,
    float* __restrict__ out, const unsigned* __restrict__ wsP,
    long long batch)
{
    __shared__ float wsum[8];
    __shared__ int s_flag[RPB];
    __shared__ int s_nflag;
    __shared__ float s_zex[ZEXB][DIM];
    __shared__ ull s_win[ZEXB];

    const int tid = threadIdx.x, lane = tid & 63, wid = tid >> 6;
    const long long R0 = (long long)blockIdx.x * RPB;

    if (tid == 0) s_nflag = 0;
    __syncthreads();

    {
        int row = tid >> 2, j = tid & 3;
        long long grow = R0 + row;
        const unsigned* p = wsP + grow * 6;
        float b1a = __uint_as_float(p[0]), b2a = __uint_as_float(p[1]);
        unsigned ia = p[2];
        float b1b = __uint_as_float(p[3]), b2b = __uint_as_float(p[4]);
        unsigned ib = p[5];

        float b1 = b1a;
        unsigned code = ia;
        if (b1b < b1a) { b1 = b1b; code = ib; }    // strict <: half0 (lower idx) wins ties
        float b2 = fminf(fminf(b2a, b2b), fmaxf(b1a, b1b));

        float4* out4 = (float4*)out;
        const float4* cb4 = (const float4*)cb;
        #pragma unroll
        for (int t = 0; t < 4; ++t)
            out4[grow * 16 + j * 4 + t] = cb4[(long long)code * 16 + j * 4 + t];

        float d = 0.f;
        if (j == 0) {
            out[batch * DIM + grow] = (float)code;   // index as exact float
            d = b1 - BIAS;                           // v1 part of loss
            if (b2 - b1 < MARGIN) {                  // ambiguous -> np-emulate
                int pp = atomicAdd(&s_nflag, 1);
                s_flag[pp] = row;
            }
        }
        #pragma unroll
        for (int m = 1; m < 64; m <<= 1) d += __shfl_xor(d, m);
        if (lane == 0) wsum[wid] = d;
    }
    __syncthreads();
    if (tid == 0) {
        float s = 0.f;
        #pragma unroll
        for (int w = 0; w < 8; ++w) s += wsum[w];
        atomicAdd(&out[batch * DIM + batch], s * (1.0f / 67108864.0f)); // /2^26
    }

    // ---- in-block np-fp32-emulated re-rank of flagged rows (R12-verbatim)
    int nf = s_nflag;
    if (nf > 0) {
        float ce[64];                                // thread's code row (tid==code)
        const float4* cb4 = (const float4*)cb;
        #pragma unroll
        for (int q = 0; q < 16; ++q) {
            float4 v = cb4[tid * 16 + q];
            ce[q * 4 + 0] = v.x; ce[q * 4 + 1] = v.y;
            ce[q * 4 + 2] = v.z; ce[q * 4 + 3] = v.w;
        }
        float s2 = np_sumsq64_sse(ce);               // np sum(cb^2), SSE order

        for (int b0 = 0; b0 < nf; b0 += ZEXB) {
            int nb = min(ZEXB, nf - b0);
            if (tid < nb * 64) {
                int i = tid >> 6, l2 = tid & 63;
                s_zex[i][l2] = z[(R0 + s_flag[b0 + i]) * DIM + l2];  // exact fp32
            }
            if (tid < ZEXB) s_win[tid] = ~0ull;
            __syncthreads();

            for (int i = 0; i < nb; ++i) {
                float s1 = np_sumsq64_sse(&s_zex[i][0]);  // np sum(z^2), SSE order
                float m = 0.f;                            // sgemm: ascending-k FMA
                #pragma unroll
                for (int k = 0; k < 64; ++k)
                    m = __builtin_fmaf(s_zex[i][k], ce[k], m);
                float dnp;
                {
                    #pragma clang fp contract(off)
                    float tt = s1 - 2.0f * m;             // keep as mul+sub (no fma)
                    dnp = tt + s2;
                }
                ull key = ((ull)fkey(dnp) << 10) | (unsigned)tid;
                #pragma unroll
                for (int mm = 1; mm < 64; mm <<= 1) {
                    ull o = __shfl_xor(key, mm);
                    if (o < key) key = o;
                }
                if (lane == 0) atomicMin(&s_win[i], key);
            }
            __syncthreads();

            for (int i = wid; i < nb; i += 8) {           // apply winners
                unsigned code = (unsigned)(s_win[i] & 0x3FFull);
                int rowb = s_flag[b0 + i];
                long long grow = R0 + rowb;
                out[grow * DIM + lane] = cb[(long long)code * DIM + lane];
                if (lane == 0) out[batch * DIM + grow] = (float)code;
            }
            __syncthreads();
        }
    }
}

// ---- fallback: R17 mono kernel (proven pass), used only if ws too small.
template <bool PRE>
__global__ __launch_bounds__(512, 4) void vq_main_mono(
    const float* __restrict__ z, const float* __restrict__ cb,
    float* __restrict__ out, const unsigned short* __restrict__ ws,
    long long batch)
{
    __shared__ __align__(16) unsigned short zhi[RPB * DIM];
    __shared__ __align__(16) unsigned short zlo[RPB * DIM];
    __shared__ float zsq[RPB];
    __shared__ float arrB[RPB][9];
    __shared__ float arrB2[RPB][9];
    __shared__ unsigned arrI[RPB][9];
    __shared__ ull cpack[RPB];
    __shared__ unsigned ck2[RPB];
    __shared__ float wsum[8];
    __shared__ int s_flag[RPB];
    __shared__ int s_nflag;
    __shared__ float s_zex[ZEXB][DIM];
    __shared__ ull s_win[ZEXB];

    const int tid = threadIdx.x, lane = tid & 63, wid = tid >> 6;
    const long long R0 = (long long)blockIdx.x * RPB;
    short8* zhi8 = (short8*)zhi;
    short8* zlo8 = (short8*)zlo;

    if (tid == 0) s_nflag = 0;

    #pragma unroll
    for (int p = 0; p < 2; ++p) {
        int L = p * 512 + tid;
        int row = L >> 3, c = L & 7;
        const float4* g = (const float4*)(z + (R0 + row) * DIM + c * 8);
        float4 f0 = g[0], f1 = g[1];
        float v[8] = {f0.x, f0.y, f0.z, f0.w, f1.x, f1.y, f1.z, f1.w};
        short8 h, l;
        float s = 0.f;
        #pragma unroll
        for (int t = 0; t < 8; ++t) {
            unsigned short hb = f2bf(v[t]);
            h[t] = (short)hb;
            l[t] = (short)f2bf(v[t] - bf2f(hb));
            s = fmaf(v[t], v[t], s);
        }
        s += __shfl_xor(s, 1);
        s += __shfl_xor(s, 2);
        s += __shfl_xor(s, 4);
        if ((tid & 7) == 0) zsq[row] = s;
        int slot = row * 8 + (c ^ (row & 7));
        zhi8[slot] = h;
        zlo8[slot] = l;
    }

    short8 bhi[4][2], blo[4][2];
    float ce2[4];
    if constexpr (PRE) {
        const unsigned short* cbhi = ws;
        const unsigned short* cblo = ws + NCODE * DIM;
        const float* ce2g = (const float*)(ws + 2 * NCODE * DIM);
        #pragma unroll
        for (int ct = 0; ct < 4; ++ct) {
            int code = wid * 64 + ct * 16 + (lane & 15);
            #pragma unroll
            for (int ks = 0; ks < 2; ++ks) {
                int k = ks * 32 + (lane >> 4) * 8;
                bhi[ct][ks] = *(const short8*)(cbhi + code * DIM + k);
                blo[ct][ks] = *(const short8*)(cblo + code * DIM + k);
            }
            ce2[ct] = ce2g[code];
        }
    } else {
        #pragma unroll
        for (int ct = 0; ct < 4; ++ct) {
            int code = wid * 64 + ct * 16 + (lane & 15);
            float s = 0.f;
            #pragma unroll
            for (int ks = 0; ks < 2; ++ks) {
                int k = ks * 32 + (lane >> 4) * 8;
                const float4* g = (const float4*)(cb + code * DIM + k);
                float4 f0 = g[0], f1 = g[1];
                float v[8] = {f0.x, f0.y, f0.z, f0.w, f1.x, f1.y, f1.z, f1.w};
                short8 h, l;
                #pragma unroll
                for (int t = 0; t < 8; ++t) {
                    unsigned short hb = f2bf(v[t]);
                    h[t] = (short)hb;
                    l[t] = (short)f2bf(v[t] - bf2f(hb));
                    s = fmaf(v[t], v[t], s);
                }
                bhi[ct][ks] = h;
                blo[ct][ks] = l;
            }
            s += __shfl_xor(s, 16);
            s += __shfl_xor(s, 32);
            ce2[ct] = s + BIAS;
        }
    }

    __syncthreads();

    for (int rt = 0; rt < 8; ++rt) {
        int arow = rt * 16 + (lane & 15);
        int swz = arow & 7;
        int c0 = (lane >> 4) ^ swz, c1 = (4 + (lane >> 4)) ^ swz;
        short8 ah0 = zhi8[arow * 8 + c0], ah1 = zhi8[arow * 8 + c1];
        short8 al0 = zlo8[arow * 8 + c0], al1 = zlo8[arow * 8 + c1];

        float b1[4] = {3.4e38f, 3.4e38f, 3.4e38f, 3.4e38f};
        float b2[4] = {3.4e38f, 3.4e38f, 3.4e38f, 3.4e38f};
        unsigned bi[4] = {0, 0, 0, 0};

        #pragma unroll
        for (int ct = 0; ct < 4; ++ct) {
            f32x4 a = {0.f, 0.f, 0.f, 0.f};
            a = __builtin_amdgcn_mfma_f32_16x16x32_bf16(ah0, bhi[ct][0], a, 0, 0, 0);
            a = __builtin_amdgcn_mfma_f32_16x16x32_bf16(ah1, bhi[ct][1], a, 0, 0, 0);
            a = __builtin_amdgcn_mfma_f32_16x16x32_bf16(ah0, blo[ct][0], a, 0, 0, 0);
            a = __builtin_amdgcn_mfma_f32_16x16x32_bf16(ah1, blo[ct][1], a, 0, 0, 0);
            a = __builtin_amdgcn_mfma_f32_16x16x32_bf16(al0, bhi[ct][0], a, 0, 0, 0);
            a = __builtin_amdgcn_mfma_f32_16x16x32_bf16(al1, bhi[ct][1], a, 0, 0, 0);
            #pragma unroll
            for (int r = 0; r < 4; ++r) {
                float v = fmaf(-2.f, a[r], ce2[ct]);
                unsigned idx = (unsigned)(wid * 64 + ct * 16 + (lane & 15));
                float nb2 = __builtin_amdgcn_fmed3f(v, b1[r], b2[r]);
                bi[r] = (v < b1[r]) ? idx : bi[r];
                b1[r] = fminf(v, b1[r]);
                b2[r] = nb2;
            }
        }

        #pragma unroll
        for (int r = 0; r < 4; ++r) {
            float x1 = b1[r], x2 = b2[r];
            unsigned xi = bi[r];
            #pragma unroll
            for (int m = 1; m <= 8; m <<= 1) {
                float ob  = __shfl_xor(x1, m);
                float ob2 = __shfl_xor(x2, m);
                unsigned oi = __shfl_xor(xi, m);
                float mx = fmaxf(x1, ob);
                x2 = fminf(fminf(x2, ob2), mx);
                xi = (ob < x1) ? oi : xi;
                x1 = fminf(x1, ob);
            }
            if ((lane & 15) == 0) {
                int row = rt * 16 + (lane >> 4) * 4 + r;
                arrB[row][wid]  = x1;
                arrB2[row][wid] = x2;
                arrI[row][wid]  = xi;
            }
        }
    }
    __syncthreads();

    if (tid < 128) {
        int row = tid;
        float b1 = arrB[row][0], b2 = arrB2[row][0];
        unsigned bi = arrI[row][0];
        #pragma unroll
        for (int w = 1; w < 8; ++w) {
            float ob = arrB[row][w];
            float ob2 = arrB2[row][w];
            unsigned oi = arrI[row][w];
            float mx = fmaxf(b1, ob);
            b2 = fminf(fminf(b2, ob2), mx);
            bi = (ob < b1) ? oi : bi;
            b1 = fminf(b1, ob);
        }
        cpack[row] = ((ull)__float_as_uint(b1) << 32) | bi;
        ck2[row] = __float_as_uint(b2);
    }
    __syncthreads();

    {
        int row = tid >> 2, j = tid & 3;
        ull best = cpack[row];
        unsigned bk2 = ck2[row];
        unsigned code = (unsigned)best;
        long long grow = R0 + row;

        float4* out4 = (float4*)out;
        const float4* cb4 = (const float4*)cb;
        #pragma unroll
        for (int t = 0; t < 4; ++t)
            out4[grow * 16 + j * 4 + t] = cb4[(long long)code * 16 + j * 4 + t];

        float d = 0.f;
        if (j == 0) {
            out[batch * DIM + grow] = (float)code;
            float v1b = __uint_as_float((unsigned)(best >> 32));
            float v2b = __uint_as_float(bk2);
            d = zsq[row] + (v1b - BIAS);
            if (v2b - v1b < MARGIN) {
                int p = atomicAdd(&s_nflag, 1);
                s_flag[p] = row;
            }
        }
        #pragma unroll
        for (int m = 1; m < 64; m <<= 1) d += __shfl_xor(d, m);
        if (lane == 0) wsum[wid] = d;
    }
    __syncthreads();
    if (tid == 0) {
        float s = 0.f;
        #pragma unroll
        for (int w = 0; w < 8; ++w) s += wsum[w];
        atomicAdd(&out[batch * DIM + batch], s * (1.0f / 67108864.0f));
    }

    int nf = s_nflag;
    if (nf > 0) {
        float ce[64];
        const float4* cb4 = (const float4*)cb;
        #pragma unroll
        for (int q = 0; q < 16; ++q) {
            float4 v = cb4[tid * 16 + q];
            ce[q * 4 + 0] = v.x; ce[q * 4 + 1] = v.y;
            ce[q * 4 + 2] = v.z; ce[q * 4 + 3] = v.w;
        }
        float s2 = np_sumsq64_sse(ce);

        for (int b0 = 0; b0 < nf; b0 += ZEXB) {
            int nb = min(ZEXB, nf - b0);
            if (tid < nb * 64) {
                int i = tid >> 6, l2 = tid & 63;
                s_zex[i][l2] = z[(R0 + s_flag[b0 + i]) * DIM + l2];
            }
            if (tid < ZEXB) s_win[tid] = ~0ull;
            __syncthreads();

            for (int i = 0; i < nb; ++i) {
                float s1 = np_sumsq64_sse(&s_zex[i][0]);
                float m = 0.f;
                #pragma unroll
                for (int k = 0; k < 64; ++k)
                    m = __builtin_fmaf(s_zex[i][k], ce[k], m);
                float dnp;
                {
                    #pragma clang fp contract(off)
                    float tt = s1 - 2.0f * m;
                    dnp = tt + s2;
                }
                ull key = ((ull)fkey(dnp) << 10) | (unsigned)tid;
                #pragma unroll
                for (int mm = 1; mm < 64; mm <<= 1) {
                    ull o = __shfl_xor(key, mm);
                    if (o < key) key = o;
                }
                if (lane == 0) atomicMin(&s_win[i], key);
            }
            __syncthreads();

            for (int i = wid; i < nb; i += 8) {
                unsigned code = (unsigned)(s_win[i] & 0x3FFull);
                int rowb = s_flag[b0 + i];
                long long grow = R0 + rowb;
                out[grow * DIM + lane] = cb[(long long)code * DIM + lane];
                if (lane == 0) out[batch * DIM + grow] = (float)code;
            }
            __syncthreads();
        }
    }
}

extern "C" void kernel_launch(void* const* d_in, const int* in_sizes, int n_in,
                              void* d_out, int out_size, void* d_ws, size_t ws_size,
                              hipStream_t stream)
{
    const float* z  = (const float*)d_in[0];
    const float* cb = (const float*)d_in[1];
    float* out = (float*)d_out;
    unsigned short* ws = (unsigned short*)d_ws;

    long long batch = (long long)in_sizes[0] / DIM;
    long long lidx = batch * DIM + batch;
    size_t ws2_need = WS_TAB + (size_t)batch * 6 * sizeof(unsigned);

    vq_zero_loss<<<1, 64, 0, stream>>>(out, lidx);
    if (d_ws != nullptr && ws_size >= ws2_need) {
        unsigned* wsP = (unsigned*)((char*)d_ws + WS_TAB);
        int nb1 = (int)((batch / PRPB) * 2);
        int nb2 = (int)(batch / RPB);
        vq_prep<<<1, NCODE, 0, stream>>>(cb, ws);
        vq_part<<<nb1, 256, 0, stream>>>(z, ws, wsP, out, batch, lidx);
        vq_merge<<<nb2, 512, 0, stream>>>(z, cb, out, wsP, batch);
    } else if (d_ws != nullptr && ws_size >= WS_TAB) {
        vq_prep<<<1, NCODE, 0, stream>>>(cb, ws);
        vq_main_mono<true><<<(int)(batch / RPB), 512, 0, stream>>>(z, cb, out, ws, batch);
    } else {
        vq_main_mono<false><<<(int)(batch / RPB), 512, 0, stream>>>(z, cb, out, ws, batch);
    }
}